// Round 9
// baseline (69.513 us; speedup 1.0000x reference)
//
#include <hip/hip_runtime.h>
#include <hip/hip_bf16.h>

namespace {

constexpr int kS  = 2048;
constexpr int kD  = 128;
constexpr int kKB = 64;              // kv rows per tile
constexpr int kNT = kS / kKB;        // 32 tiles
constexpr int kTileUS = 1024 * 8;    // 8192 ushorts = 16KB per (64-row) tile image
constexpr size_t kImgUShorts = (size_t)16 * 32 * kTileUS;   // 8 MB per image set

typedef __attribute__((ext_vector_type(8)))  short bf16x8;
typedef __attribute__((ext_vector_type(16))) float f32x16;
typedef __attribute__((ext_vector_type(4)))  unsigned int u32x4;

__device__ inline unsigned short f2bf(float f) {
  return __builtin_bit_cast(unsigned short, __float2bfloat16(f));
}
__device__ inline unsigned pk2(float lo, float hi) {
  return (unsigned)f2bf(lo) | ((unsigned)f2bf(hi) << 16);
}
__device__ inline float fexp2(float x) { return __builtin_amdgcn_exp2f(x); }

__device__ inline void gload_lds16(const void* g, void* l) {
  __builtin_amdgcn_global_load_lds(
      (const __attribute__((address_space(1))) unsigned int*)g,
      (__attribute__((address_space(3))) unsigned int*)l, 16, 0, 0);
}

// ---------------- pre-pass: f32 -> bf16, swizzled 64-row tile images ----------------
// K image per (b,t): chunk CH = k*16+s (k<64,s<16): holds K[t*64+k][d8*8..+8], d8 = s^(k&15)
// V image per (b,t): chunk CH = d*8+s  (d<128,s<8): holds V[t*64+(s^(d&7))*8+j][d], j=0..7
__global__ __launch_bounds__(256)
void convert_kv(const float* __restrict__ K, const float* __restrict__ V,
                unsigned short* __restrict__ Kws, unsigned short* __restrict__ Vws)
{
  const int tid = threadIdx.x;
  const int gid = blockIdx.x & 511;
  const int b = gid >> 5, t = gid & 31;
  if (blockIdx.x < 512) {
    const float* src = K + ((size_t)b * kS + t * kKB) * kD;
    unsigned short* dst = Kws + (size_t)gid * kTileUS;
#pragma unroll
    for (int i = 0; i < 4; ++i) {
      const int CH = i * 256 + tid;            // 0..1023
      const int k = CH >> 4, s = CH & 15;
      const int d8 = s ^ (k & 15);
      const float* p = src + (size_t)k * kD + d8 * 8;
      float4 a = *reinterpret_cast<const float4*>(p);
      float4 c = *reinterpret_cast<const float4*>(p + 4);
      bf16x8 o;
      o[0] = (short)f2bf(a.x); o[1] = (short)f2bf(a.y);
      o[2] = (short)f2bf(a.z); o[3] = (short)f2bf(a.w);
      o[4] = (short)f2bf(c.x); o[5] = (short)f2bf(c.y);
      o[6] = (short)f2bf(c.z); o[7] = (short)f2bf(c.w);
      *reinterpret_cast<bf16x8*>(dst + (size_t)CH * 8) = o;
    }
  } else {
    __shared__ unsigned short VT[128 * 72];    // [d][k], 144B rows (16B-aligned)
    const float* src = V + ((size_t)b * kS + t * kKB) * kD;
#pragma unroll
    for (int i = 0; i < 8; ++i) {
      const int idx = i * 256 + tid;           // 0..2047 = 64k x 32 float4
      const int k = idx >> 5, d4 = idx & 31;
      float4 v = *reinterpret_cast<const float4*>(src + (size_t)k * kD + d4 * 4);
      VT[(d4 * 4 + 0) * 72 + k] = f2bf(v.x);
      VT[(d4 * 4 + 1) * 72 + k] = f2bf(v.y);
      VT[(d4 * 4 + 2) * 72 + k] = f2bf(v.z);
      VT[(d4 * 4 + 3) * 72 + k] = f2bf(v.w);
    }
    __syncthreads();
    unsigned short* dst = Vws + (size_t)gid * kTileUS;
#pragma unroll
    for (int i = 0; i < 4; ++i) {
      const int CH = i * 256 + tid;            // 0..1023
      const int d = CH >> 3, s = CH & 7;
      const int k8 = s ^ (d & 7);
      bf16x8 v = *reinterpret_cast<const bf16x8*>(&VT[d * 72 + k8 * 8]);
      *reinterpret_cast<bf16x8*>(dst + (size_t)CH * 8) = v;
    }
  }
}

// ---------------- main attention kernel: 2 independent blocks/CU ----------------
// 256 thr = 4 waves = 2 qg(32q) x 2 ksp(32k). KVB=64, 32 tiles. Q in regs.
// LDS 64KB: K dbuf [0,32K), V dbuf [32K,64K). Pipeline: iter t = QK(t+1) then PV(t).
__global__ __launch_bounds__(256, 2)
void attn_fwd(const float* __restrict__ Q,
              const unsigned short* __restrict__ Kws,
              const unsigned short* __restrict__ Vws,
              float* __restrict__ O)
{
  __shared__ __align__(16) unsigned char smem[65536];
  __shared__ float mls[2 * 2 * 32];

  const int tid  = threadIdx.x;
  const int wv   = tid >> 6;          // 0..3
  const int qg   = wv >> 1;           // 0..1 : 32 q-rows each
  const int ksp  = wv & 1;            // 0..1 : 32 kv-rows each
  const int lane = tid & 63;
  const int l31  = lane & 31;
  const int hi   = lane >> 5;
  const int m15  = l31 & 15;
  const int m7   = l31 & 7;

  // XCD-locality: 2 batches per XCD
  const int bid   = blockIdx.x;
  const int xcd   = bid & 7;
  const int slot  = bid >> 3;          // 0..63
  const int batch = xcd * 2 + (slot >> 5);
  const int qt    = slot & 31;         // 64-row q tile

  const float* Qb = Q + (size_t)batch * kS * kD;
  float*       Ob = O + (size_t)batch * kS * kD;
  const int qrow0 = qt * 64 + qg * 32;

  auto stageK = [&](int t, int buf) {
    const unsigned short* src = Kws + (size_t)(batch * 32 + t) * kTileUS + (wv * 256 + lane) * 8;
    unsigned char* kd = smem + buf * 16384 + wv * 4096;
    gload_lds16(src,            kd);
    gload_lds16(src + 64 * 8,   kd + 1024);
    gload_lds16(src + 128 * 8,  kd + 2048);
    gload_lds16(src + 192 * 8,  kd + 3072);
  };
  auto stageV = [&](int t, int buf) {
    const unsigned short* src = Vws + (size_t)(batch * 32 + t) * kTileUS + (wv * 256 + lane) * 8;
    unsigned char* vd = smem + 32768 + buf * 16384 + wv * 4096;
    gload_lds16(src,            vd);
    gload_lds16(src + 64 * 8,   vd + 1024);
    gload_lds16(src + 128 * 8,  vd + 2048);
    gload_lds16(src + 192 * 8,  vd + 3072);
  };

  stageK(0, 0); stageV(0, 0); stageK(1, 1);

  // ---- Q fragments in regs: col q = l31, rows d = c*16 + hi*8 + e
  constexpr float kQScale = 0.08838834764831845f * 1.4426950408889634f; // 1/sqrt(128)*log2(e)
  bf16x8 qf[8];
#pragma unroll
  for (int c = 0; c < 8; ++c) {
    const float* p = Qb + (size_t)(qrow0 + l31) * kD + c * 16 + hi * 8;
    float4 a = *reinterpret_cast<const float4*>(p);
    float4 b = *reinterpret_cast<const float4*>(p + 4);
    bf16x8 f;
    f[0] = (short)f2bf(a.x * kQScale); f[1] = (short)f2bf(a.y * kQScale);
    f[2] = (short)f2bf(a.z * kQScale); f[3] = (short)f2bf(a.w * kQScale);
    f[4] = (short)f2bf(b.x * kQScale); f[5] = (short)f2bf(b.y * kQScale);
    f[6] = (short)f2bf(b.z * kQScale); f[7] = (short)f2bf(b.w * kQScale);
    qf[c] = f;
  }

  f32x16 acc[4];
#pragma unroll
  for (int dt = 0; dt < 4; ++dt)
#pragma unroll
    for (int r = 0; r < 16; ++r) acc[dt][r] = 0.f;
  float mrun = -1e30f, lrun = 0.f;
  bf16x8 pa0, pa1;

  __syncthreads();   // drains prologue DMA

  const unsigned short* Ksm = reinterpret_cast<const unsigned short*>(smem);
  const unsigned short* Vsm = reinterpret_cast<const unsigned short*>(smem + 32768);
  const int kRowBase = (ksp * 32 + l31) * 128;   // K row stride 128 ushorts (256B)

  auto qk = [&](int kb) -> f32x16 {
    f32x16 sc;
#pragma unroll
    for (int r = 0; r < 16; ++r) sc[r] = 0.f;
    __builtin_amdgcn_s_setprio(1);
#pragma unroll
    for (int c = 0; c < 8; ++c) {
      const int s = ((c << 1) | hi) ^ m15;
      bf16x8 kf = *reinterpret_cast<const bf16x8*>(&Ksm[kb * 8192 + kRowBase + s * 8]);
      sc = __builtin_amdgcn_mfma_f32_32x32x16_bf16(kf, qf[c], sc, 0, 0, 0);
    }
    __builtin_amdgcn_s_setprio(0);
    return sc;
  };
  auto treemax = [&](const f32x16& sc) {
    float m0 = sc[0];
#pragma unroll
    for (int r = 1; r < 16; ++r) m0 = fmaxf(m0, sc[r]);
    return fmaxf(m0, __shfl_xor(m0, 32));
  };
  auto pv = [&](int vb) {
    const int o0 = (ksp << 2) | hi;              // base k-octet of this wave
    __builtin_amdgcn_s_setprio(1);
#pragma unroll
    for (int dt = 0; dt < 4; ++dt) {
      const int vRow = vb * 8192 + (dt * 32 + l31) * 64;   // V row stride 64 ushorts
      bf16x8 vf0 = *reinterpret_cast<const bf16x8*>(&Vsm[vRow + (o0 ^ m7) * 8]);
      acc[dt] = __builtin_amdgcn_mfma_f32_32x32x16_bf16(vf0, pa0, acc[dt], 0, 0, 0);
      bf16x8 vf1 = *reinterpret_cast<const bf16x8*>(&Vsm[vRow + ((o0 ^ 2) ^ m7) * 8]);
      acc[dt] = __builtin_amdgcn_mfma_f32_32x32x16_bf16(vf1, pa1, acc[dt], 0, 0, 0);
    }
    __builtin_amdgcn_s_setprio(0);
  };
  auto pack = [&](const f32x16& p) {
    unsigned a0 = pk2(p[0], p[1]),   a1 = pk2(p[2],  p[3]);
    unsigned a2 = pk2(p[4], p[5]),   a3 = pk2(p[6],  p[7]);
    unsigned b0 = pk2(p[8], p[9]),   b1 = pk2(p[10], p[11]);
    unsigned b2 = pk2(p[12], p[13]), b3 = pk2(p[14], p[15]);
    asm("v_permlane32_swap_b32 %0, %1" : "+v"(a0), "+v"(a2));
    asm("v_permlane32_swap_b32 %0, %1" : "+v"(a1), "+v"(a3));
    asm("v_permlane32_swap_b32 %0, %1" : "+v"(b0), "+v"(b2));
    asm("v_permlane32_swap_b32 %0, %1" : "+v"(b1), "+v"(b3));
    u32x4 w0 = {a0, a1, a2, a3};
    u32x4 w1 = {b0, b1, b2, b3};
    pa0 = __builtin_bit_cast(bf16x8, w0);
    pa1 = __builtin_bit_cast(bf16x8, w1);
  };

  // ---- pipeline prologue: tile 0 QK+softmax+pack
  {
    f32x16 sc = qk(0);
    mrun = treemax(sc);
    float rs = 0.f;
#pragma unroll
    for (int r = 0; r < 16; ++r) { sc[r] = fexp2(sc[r] - mrun); rs += sc[r]; }
    rs += __shfl_xor(rs, 32);
    lrun = rs;
    pack(sc);
  }
  __syncthreads();   // all waves done reading Kbuf0 before restaging it

  // ---- main pipelined loop: iter t does QK(t+1) then PV(t)
  for (int t = 0; t < kNT - 1; ++t) {
    const int kb = (t + 1) & 1, vb = t & 1;
    if (t + 2 < kNT) stageK(t + 2, vb);
    stageV(t + 1, kb);

    f32x16 sc = qk(kb);                   // QK(t+1)
    const float mt = treemax(sc);
    const bool need = !__all(mt - mrun <= 8.0f);   // T13 defer-max
    const float mnew = need ? fmaxf(mrun, mt) : mrun;

    pv(vb);                               // PV(t): MFMA, independent of softmax below

    float rs = 0.f;
#pragma unroll
    for (int r = 0; r < 16; ++r) { sc[r] = fexp2(sc[r] - mnew); rs += sc[r]; }
    rs += __shfl_xor(rs, 32);
    if (need) {
      const float corr = fexp2(mrun - mnew);
      lrun *= corr;
#pragma unroll
      for (int dt = 0; dt < 4; ++dt)
#pragma unroll
        for (int r = 0; r < 16; ++r) acc[dt][r] *= corr;
    }
    lrun += rs;
    mrun = mnew;
    pack(sc);

    __syncthreads();
  }

  // ---- epilogue: PV(last tile)
  pv((kNT - 1) & 1);
  __syncthreads();   // all K/V LDS reads done before scratch overlay

  // ---- 2-way split-k merge; scratch overlays staging (swizzled banks)
  float* scr = reinterpret_cast<float*>(smem);   // 2 regions x [32 q][128 d]
  auto scrAt = [&](int reg, int q, int d) -> float& {
    return scr[reg * 4096 + q * 128 + (d ^ ((q & 7) << 2))];
  };
  auto drow = [&](int r) { return (r & 3) + 8 * (r >> 2) + 4 * hi; };

  if (ksp == 1) {
#pragma unroll
    for (int dt = 0; dt < 4; ++dt)
#pragma unroll
      for (int r = 0; r < 16; ++r)
        scrAt(qg, l31, dt * 32 + drow(r)) = acc[dt][r];
    mls[(qg * 2 + 0) * 32 + l31] = mrun;
    mls[(qg * 2 + 1) * 32 + l31] = lrun;
  }
  __syncthreads();
  if (ksp == 0) {
    const float m2 = mls[(qg * 2 + 0) * 32 + l31];
    const float l2 = mls[(qg * 2 + 1) * 32 + l31];
    const float mm = fmaxf(mrun, m2);
    const float w1 = fexp2(mrun - mm), w2 = fexp2(m2 - mm);
    const float inv = 1.0f / (lrun * w1 + l2 * w2);
#pragma unroll
    for (int dt = 0; dt < 4; ++dt)
#pragma unroll
      for (int r = 0; r < 16; ++r) {
        const int d = dt * 32 + drow(r);
        float o1 = scrAt(qg, l31, d);
        scrAt(qg, l31, d) = (acc[dt][r] * w1 + o1 * w2) * inv;
      }
  }
  __syncthreads();
  // coalesced O store: 64 q-rows x 128 d from scratch
  const int krow = tid >> 5, c4 = tid & 31;
#pragma unroll
  for (int i = 0; i < 8; ++i) {
    const int row = i * 8 + krow;          // 0..63
    const int q = row & 31;
    float4 val = *reinterpret_cast<const float4*>(
        &scr[(row >> 5) * 4096 + q * 128 + ((c4 * 4) ^ ((q & 7) << 2))]);
    *reinterpret_cast<float4*>(&Ob[(size_t)(qt * 64 + row) * kD + c4 * 4]) = val;
  }
}

} // namespace

extern "C" void kernel_launch(void* const* d_in, const int* in_sizes, int n_in,
                              void* d_out, int out_size, void* d_ws, size_t ws_size,
                              hipStream_t stream) {
  const float* Q = (const float*)d_in[0];
  const float* K = (const float*)d_in[1];
  const float* V = (const float*)d_in[2];
  float* O = (float*)d_out;
  (void)in_sizes; (void)n_in; (void)out_size; (void)ws_size;

  unsigned short* Kws = (unsigned short*)d_ws;
  unsigned short* Vws = Kws + kImgUShorts;

  hipLaunchKernelGGL(convert_kv, dim3(1024), dim3(256), 0, stream, K, V, Kws, Vws);
  hipLaunchKernelGGL(attn_fwd,   dim3(512),  dim3(256), 0, stream, Q, Kws, Vws, O);
}

// Round 10
// 64.804 us; speedup vs baseline: 1.0727x; 1.0727x over previous
//
#include <hip/hip_runtime.h>
#include <hip/hip_bf16.h>

namespace {

constexpr int kS  = 2048;
constexpr int kD  = 128;
constexpr int kKB = 64;              // kv rows per tile
constexpr int kNT = kS / kKB;        // 32 tiles
constexpr int kTileUS = 1024 * 8;    // 8192 ushorts = 16KB per (64-row) tile image
constexpr size_t kImgUShorts = (size_t)16 * 32 * kTileUS;   // 8 MB per image set

typedef __attribute__((ext_vector_type(8)))  short bf16x8;
typedef __attribute__((ext_vector_type(16))) float f32x16;
typedef __attribute__((ext_vector_type(4)))  unsigned int u32x4;

__device__ inline unsigned short f2bf(float f) {
  return __builtin_bit_cast(unsigned short, __float2bfloat16(f));
}
__device__ inline unsigned pk2(float lo, float hi) {
  return (unsigned)f2bf(lo) | ((unsigned)f2bf(hi) << 16);
}
__device__ inline float fexp2(float x) { return __builtin_amdgcn_exp2f(x); }

__device__ inline void gload_lds16(const void* g, void* l) {
  __builtin_amdgcn_global_load_lds(
      (const __attribute__((address_space(1))) unsigned int*)g,
      (__attribute__((address_space(3))) unsigned int*)l, 16, 0, 0);
}

// ---------------- pre-pass: f32 -> bf16, swizzled 64-row tile images (verified R9) ----------------
__global__ __launch_bounds__(256)
void convert_kv(const float* __restrict__ K, const float* __restrict__ V,
                unsigned short* __restrict__ Kws, unsigned short* __restrict__ Vws)
{
  const int tid = threadIdx.x;
  const int gid = blockIdx.x & 511;
  const int b = gid >> 5, t = gid & 31;
  if (blockIdx.x < 512) {
    const float* src = K + ((size_t)b * kS + t * kKB) * kD;
    unsigned short* dst = Kws + (size_t)gid * kTileUS;
#pragma unroll
    for (int i = 0; i < 4; ++i) {
      const int CH = i * 256 + tid;            // 0..1023
      const int k = CH >> 4, s = CH & 15;
      const int d8 = s ^ (k & 15);
      const float* p = src + (size_t)k * kD + d8 * 8;
      float4 a = *reinterpret_cast<const float4*>(p);
      float4 c = *reinterpret_cast<const float4*>(p + 4);
      bf16x8 o;
      o[0] = (short)f2bf(a.x); o[1] = (short)f2bf(a.y);
      o[2] = (short)f2bf(a.z); o[3] = (short)f2bf(a.w);
      o[4] = (short)f2bf(c.x); o[5] = (short)f2bf(c.y);
      o[6] = (short)f2bf(c.z); o[7] = (short)f2bf(c.w);
      *reinterpret_cast<bf16x8*>(dst + (size_t)CH * 8) = o;
    }
  } else {
    __shared__ unsigned short VT[128 * 72];    // [d][k]
    const float* src = V + ((size_t)b * kS + t * kKB) * kD;
#pragma unroll
    for (int i = 0; i < 8; ++i) {
      const int idx = i * 256 + tid;
      const int k = idx >> 5, d4 = idx & 31;
      float4 v = *reinterpret_cast<const float4*>(src + (size_t)k * kD + d4 * 4);
      VT[(d4 * 4 + 0) * 72 + k] = f2bf(v.x);
      VT[(d4 * 4 + 1) * 72 + k] = f2bf(v.y);
      VT[(d4 * 4 + 2) * 72 + k] = f2bf(v.z);
      VT[(d4 * 4 + 3) * 72 + k] = f2bf(v.w);
    }
    __syncthreads();
    unsigned short* dst = Vws + (size_t)gid * kTileUS;
#pragma unroll
    for (int i = 0; i < 4; ++i) {
      const int CH = i * 256 + tid;            // 0..1023
      const int d = CH >> 3, s = CH & 7;
      const int k8 = s ^ (d & 7);
      bf16x8 v = *reinterpret_cast<const bf16x8*>(&VT[d * 72 + k8 * 8]);
      *reinterpret_cast<bf16x8*>(dst + (size_t)CH * 8) = v;
    }
  }
}

// ---------------- main attention kernel: counted-vmcnt, 3-deep staging ----------------
// 256 blocks x 512 thr = 8 waves (4 qg x 2 ksp). KVB=64, 32 tiles. Q in regs.
// LDS: K bufs 3x16KB [0,49152), V bufs 3x16KB [49152,98304). No full drains in loop.
__global__ __launch_bounds__(512, 2)
void attn_fwd(const float* __restrict__ Q,
              const unsigned short* __restrict__ Kws,
              const unsigned short* __restrict__ Vws,
              float* __restrict__ O)
{
  __shared__ __align__(16) unsigned char smem[98304];
  __shared__ float mls[4 * 2 * 32];

  const int tid  = threadIdx.x;
  const int wv   = tid >> 6;          // 0..7
  const int qg   = wv >> 1;           // 0..3 : 32 q-rows each
  const int ksp  = wv & 1;            // 0..1 : 32 kv-rows each
  const int lane = tid & 63;
  const int l31  = lane & 31;
  const int hi   = lane >> 5;
  const int m15  = l31 & 15;
  const int m7   = l31 & 7;

  // XCD-locality: 2 batches per XCD
  const int bid   = blockIdx.x;
  const int xcd   = bid & 7;
  const int slot  = bid >> 3;          // 0..31
  const int batch = xcd * 2 + (slot >> 4);
  const int qt    = slot & 15;         // 128-row q tile

  const float* Qb = Q + (size_t)batch * kS * kD;
  float*       Ob = O + (size_t)batch * kS * kD;
  const int qrow0 = qt * 128 + qg * 32;

  auto stageK = [&](int t, int buf) {  // 2 vmcnt ops/wave
    const unsigned short* src = Kws + (size_t)(batch * 32 + t) * kTileUS + (wv * 128 + lane) * 8;
    unsigned char* kd = smem + buf * 16384 + wv * 2048;
    gload_lds16(src,          kd);
    gload_lds16(src + 64 * 8, kd + 1024);
  };
  auto stageV = [&](int t, int buf) {  // 2 vmcnt ops/wave
    const unsigned short* src = Vws + (size_t)(batch * 32 + t) * kTileUS + (wv * 128 + lane) * 8;
    unsigned char* vd = smem + 49152 + buf * 16384 + wv * 2048;
    gload_lds16(src,          vd);
    gload_lds16(src + 64 * 8, vd + 1024);
  };

  // ---- Q fragments in regs first (their compiler-waits see zero staging in flight)
  constexpr float kQScale = 0.08838834764831845f * 1.4426950408889634f; // 1/sqrt(128)*log2(e)
  bf16x8 qf[8];
#pragma unroll
  for (int c = 0; c < 8; ++c) {
    const float* p = Qb + (size_t)(qrow0 + l31) * kD + c * 16 + hi * 8;
    float4 a = *reinterpret_cast<const float4*>(p);
    float4 b = *reinterpret_cast<const float4*>(p + 4);
    bf16x8 f;
    f[0] = (short)f2bf(a.x * kQScale); f[1] = (short)f2bf(a.y * kQScale);
    f[2] = (short)f2bf(a.z * kQScale); f[3] = (short)f2bf(a.w * kQScale);
    f[4] = (short)f2bf(b.x * kQScale); f[5] = (short)f2bf(b.y * kQScale);
    f[6] = (short)f2bf(b.z * kQScale); f[7] = (short)f2bf(b.w * kQScale);
    qf[c] = f;
  }

  // ---- prologue staging: K0,V0,K1 (6 ops in flight)
  stageK(0, 0); stageV(0, 0); stageK(1, 1);

  f32x16 acc[4];
#pragma unroll
  for (int dt = 0; dt < 4; ++dt)
#pragma unroll
    for (int r = 0; r < 16; ++r) acc[dt][r] = 0.f;
  float mrun = -1e30f, lrun = 0.f;
  bf16x8 pa0, pa1;

  const unsigned short* Ksm = reinterpret_cast<const unsigned short*>(smem);
  const unsigned short* Vsm = reinterpret_cast<const unsigned short*>(smem + 49152);
  const int kRowBase = (ksp * 32 + l31) * 128;   // K row stride 128 ushorts (256B)

  auto qk = [&](int kb) -> f32x16 {
    f32x16 sc;
#pragma unroll
    for (int r = 0; r < 16; ++r) sc[r] = 0.f;
    __builtin_amdgcn_s_setprio(1);
#pragma unroll
    for (int c = 0; c < 8; ++c) {
      const int s = ((c << 1) | hi) ^ m15;
      bf16x8 kf = *reinterpret_cast<const bf16x8*>(&Ksm[kb * 8192 + kRowBase + s * 8]);
      sc = __builtin_amdgcn_mfma_f32_32x32x16_bf16(kf, qf[c], sc, 0, 0, 0);
    }
    __builtin_amdgcn_s_setprio(0);
    return sc;
  };
  auto treemax = [&](const f32x16& sc) {
    float m0 = sc[0];
#pragma unroll
    for (int r = 1; r < 16; ++r) m0 = fmaxf(m0, sc[r]);
    return fmaxf(m0, __shfl_xor(m0, 32));
  };
  auto pv = [&](int vb) {
    const int o0 = (ksp << 2) | hi;
    __builtin_amdgcn_s_setprio(1);
#pragma unroll
    for (int dt = 0; dt < 4; ++dt) {
      const int vRow = vb * 8192 + (dt * 32 + l31) * 64;   // V row stride 64 ushorts
      bf16x8 vf0 = *reinterpret_cast<const bf16x8*>(&Vsm[vRow + (o0 ^ m7) * 8]);
      acc[dt] = __builtin_amdgcn_mfma_f32_32x32x16_bf16(vf0, pa0, acc[dt], 0, 0, 0);
      bf16x8 vf1 = *reinterpret_cast<const bf16x8*>(&Vsm[vRow + ((o0 ^ 2) ^ m7) * 8]);
      acc[dt] = __builtin_amdgcn_mfma_f32_32x32x16_bf16(vf1, pa1, acc[dt], 0, 0, 0);
    }
    __builtin_amdgcn_s_setprio(0);
  };
  auto pack = [&](const f32x16& p) {
    unsigned a0 = pk2(p[0], p[1]),   a1 = pk2(p[2],  p[3]);
    unsigned a2 = pk2(p[4], p[5]),   a3 = pk2(p[6],  p[7]);
    unsigned b0 = pk2(p[8], p[9]),   b1 = pk2(p[10], p[11]);
    unsigned b2 = pk2(p[12], p[13]), b3 = pk2(p[14], p[15]);
    asm("v_permlane32_swap_b32 %0, %1" : "+v"(a0), "+v"(a2));
    asm("v_permlane32_swap_b32 %0, %1" : "+v"(a1), "+v"(a3));
    asm("v_permlane32_swap_b32 %0, %1" : "+v"(b0), "+v"(b2));
    asm("v_permlane32_swap_b32 %0, %1" : "+v"(b1), "+v"(b3));
    u32x4 w0 = {a0, a1, a2, a3};
    u32x4 w1 = {b0, b1, b2, b3};
    pa0 = __builtin_bit_cast(bf16x8, w0);
    pa1 = __builtin_bit_cast(bf16x8, w1);
  };

  // ---- prologue compute: tile 0 (needs K0 only -> leave V0,K1 in flight)
  asm volatile("s_waitcnt vmcnt(4)" ::: "memory");
  __builtin_amdgcn_sched_barrier(0);
  __builtin_amdgcn_s_barrier();          // all waves' K0 chunks landed
  __builtin_amdgcn_sched_barrier(0);
  {
    f32x16 sc = qk(0);
    mrun = treemax(sc);
    float rs = 0.f;
#pragma unroll
    for (int r = 0; r < 16; ++r) { sc[r] = fexp2(sc[r] - mrun); rs += sc[r]; }
    rs += __shfl_xor(rs, 32);
    lrun = rs;
    pack(sc);
  }

  // ---- main loop: iter t = QK(t+1) then PV(t); counted vmcnt, raw barriers
  int vRead = 0, kRead = 1, kStage = 2;
  for (int t = 0; t < kNT - 1; ++t) {
    if (t < kNT - 2) {
      stageK(t + 2, kStage);             // overwrites K[t-1] (read 2 barriers ago)
      stageV(t + 1, kRead);              // overwrites V[t-2] (read 2 barriers ago)
      asm volatile("s_waitcnt vmcnt(4)" ::: "memory");   // K[t+1],V[t] landed (mine)
    } else {
      stageV(t + 1, kRead);
      asm volatile("s_waitcnt vmcnt(2)" ::: "memory");
    }
    __builtin_amdgcn_sched_barrier(0);
    __builtin_amdgcn_s_barrier();        // everyone's K[t+1],V[t] chunks landed
    __builtin_amdgcn_sched_barrier(0);

    f32x16 sc = qk(kRead);               // QK(t+1)
    const float mt = treemax(sc);
    const bool need = !__all(mt - mrun <= 8.0f);   // T13 defer-max
    const float mnew = need ? fmaxf(mrun, mt) : mrun;

    pv(vRead);                           // PV(t), pa from previous iteration

    float rs = 0.f;
#pragma unroll
    for (int r = 0; r < 16; ++r) { sc[r] = fexp2(sc[r] - mnew); rs += sc[r]; }
    rs += __shfl_xor(rs, 32);
    if (need) {
      const float corr = fexp2(mrun - mnew);
      lrun *= corr;
#pragma unroll
      for (int dt = 0; dt < 4; ++dt)
#pragma unroll
        for (int r = 0; r < 16; ++r) acc[dt][r] *= corr;
    }
    lrun += rs;
    mrun = mnew;
    pack(sc);

    vRead = kRead; kRead = kStage; kStage = (kStage == 2) ? 0 : kStage + 1;
  }

  // ---- epilogue: PV(last tile) — its V staged last iter, still in flight
  asm volatile("s_waitcnt vmcnt(0)" ::: "memory");
  __builtin_amdgcn_sched_barrier(0);
  __builtin_amdgcn_s_barrier();
  __builtin_amdgcn_sched_barrier(0);
  pv(vRead);
  __syncthreads();   // full drain ok (once): all LDS reads done before scratch overlay

  // ---- 2-way split-k merge; scratch overlays staging (swizzled banks)
  float* scr = reinterpret_cast<float*>(smem);   // 4 regions x [32 q][128 d] = 64KB
  auto scrAt = [&](int reg, int q, int d) -> float& {
    return scr[reg * 4096 + q * 128 + (d ^ ((q & 7) << 2))];
  };
  auto drow = [&](int r) { return (r & 3) + 8 * (r >> 2) + 4 * hi; };

  if (ksp == 1) {
#pragma unroll
    for (int dt = 0; dt < 4; ++dt)
#pragma unroll
      for (int r = 0; r < 16; ++r)
        scrAt(qg, l31, dt * 32 + drow(r)) = acc[dt][r];
    mls[(qg * 2 + 0) * 32 + l31] = mrun;
    mls[(qg * 2 + 1) * 32 + l31] = lrun;
  }
  __syncthreads();
  if (ksp == 0) {
    const float m2 = mls[(qg * 2 + 0) * 32 + l31];
    const float l2 = mls[(qg * 2 + 1) * 32 + l31];
    const float mm = fmaxf(mrun, m2);
    const float w1 = fexp2(mrun - mm), w2 = fexp2(m2 - mm);
    const float inv = 1.0f / (lrun * w1 + l2 * w2);
#pragma unroll
    for (int dt = 0; dt < 4; ++dt)
#pragma unroll
      for (int r = 0; r < 16; ++r) {
        const int d = dt * 32 + drow(r);
        float o1 = scrAt(qg, l31, d);
        scrAt(qg, l31, d) = (acc[dt][r] * w1 + o1 * w2) * inv;
      }
  }
  __syncthreads();
  // coalesced O store: 128 q-rows x 128 d from scratch
  const int krow = tid >> 5, c4 = tid & 31;
#pragma unroll
  for (int i = 0; i < 8; ++i) {
    const int row = i * 16 + krow;         // 0..127
    const int q = row & 31;
    float4 val = *reinterpret_cast<const float4*>(
        &scr[(row >> 5) * 4096 + q * 128 + ((c4 * 4) ^ ((q & 7) << 2))]);
    *reinterpret_cast<float4*>(&Ob[(size_t)(qt * 128 + row) * kD + c4 * 4]) = val;
  }
}

} // namespace

extern "C" void kernel_launch(void* const* d_in, const int* in_sizes, int n_in,
                              void* d_out, int out_size, void* d_ws, size_t ws_size,
                              hipStream_t stream) {
  const float* Q = (const float*)d_in[0];
  const float* K = (const float*)d_in[1];
  const float* V = (const float*)d_in[2];
  float* O = (float*)d_out;
  (void)in_sizes; (void)n_in; (void)out_size; (void)ws_size;

  unsigned short* Kws = (unsigned short*)d_ws;
  unsigned short* Vws = Kws + kImgUShorts;

  hipLaunchKernelGGL(convert_kv, dim3(1024), dim3(256), 0, stream, K, V, Kws, Vws);
  hipLaunchKernelGGL(attn_fwd,   dim3(256),  dim3(512), 0, stream, Q, Kws, Vws, O);
}